// Round 2
// baseline (268.134 us; speedup 1.0000x reference)
//
#include <hip/hip_runtime.h>

// IntraAgg: out[b] = concat(mean_k emb[idx[b,k]], self[b] - mean)
// B=50000, K=32, D=128, all f32. One wave per node; row = 64 lanes x float2.

#define DDIM 128
#define KNEI 32

__global__ __launch_bounds__(256) void intra_agg_kernel(
    const float* __restrict__ emb,
    const float* __restrict__ selff,
    const int* __restrict__ idx,
    float* __restrict__ out,
    int B)
{
    const int wave = blockIdx.x * 4 + (threadIdx.x >> 6);
    if (wave >= B) return;
    const int lane = threadIdx.x & 63;

    const float2* __restrict__ embv = reinterpret_cast<const float2*>(emb);
    const int* __restrict__ nid = idx + (size_t)wave * KNEI;

    float sx = 0.0f, sy = 0.0f;
#pragma unroll
    for (int k = 0; k < KNEI; ++k) {
        const int r = nid[k];  // wave-uniform -> scalar load
        const float2 v = embv[(size_t)r * (DDIM / 2) + lane];
        sx += v.x;
        sy += v.y;
    }

    const float inv = 1.0f / (float)KNEI;
    const float mx = sx * inv;
    const float my = sy * inv;

    const float2 s = reinterpret_cast<const float2*>(selff)[(size_t)wave * (DDIM / 2) + lane];

    float2* __restrict__ o = reinterpret_cast<float2*>(out);
    const size_t ob = (size_t)wave * DDIM;  // row = 256 floats = 128 float2
    o[ob + lane] = make_float2(mx, my);
    o[ob + 64 + lane] = make_float2(s.x - mx, s.y - my);
}

extern "C" void kernel_launch(void* const* d_in, const int* in_sizes, int n_in,
                              void* d_out, int out_size, void* d_ws, size_t ws_size,
                              hipStream_t stream) {
    const float* emb = (const float*)d_in[0];
    const float* selff = (const float*)d_in[1];
    const int* idx = (const int*)d_in[2];
    float* out = (float*)d_out;

    const int B = in_sizes[2] / KNEI;  // 50000
    const int blocks = (B + 3) / 4;    // 4 waves per 256-thread block
    intra_agg_kernel<<<blocks, 256, 0, stream>>>(emb, selff, idx, out, B);
}